// Round 3
// baseline (180.388 us; speedup 1.0000x reference)
//
#include <hip/hip_runtime.h>
#include <hip/hip_bf16.h>

#define NBLK 8
#define DIN 512
#define DOUT 512
#define NFEAT 4096      // NBLK * DIN
#define BATCH 8192
#define NT 16           // DIN / 32 K-steps

typedef __attribute__((ext_vector_type(8))) short short8;
typedef __attribute__((ext_vector_type(4))) float f32x4;

static __device__ __forceinline__ short f2bf16(float f) {
  __bf16 h = (__bf16)f;               // RNE; compiler packs pairs into v_cvt_pk_bf16_f32
  return __builtin_bit_cast(short, h);
}

static __device__ __forceinline__ short8 cvt8(f32x4 lo, f32x4 hi) {
  short8 o;
  o[0] = f2bf16(lo[0]); o[1] = f2bf16(lo[1]); o[2] = f2bf16(lo[2]); o[3] = f2bf16(lo[3]);
  o[4] = f2bf16(hi[0]); o[5] = f2bf16(hi[1]); o[6] = f2bf16(hi[2]); o[7] = f2bf16(hi[3]);
  return o;
}

// Pre-pass: W [8][512][512] fp32 -> Wp fragment-major bf16 so the main kernel's
// B-fragment is one coalesced short8 load:
//   Wp[(((nb*32 + cb)*16 + t)*64 + lane)*8 + j]
//     = bf16( W[nb][cb*16 + (lane&15)][t*32 + (lane>>4)*8 + j] )
__global__ __launch_bounds__(256) void wprep_kernel(const float* __restrict__ W,
                                                    short* __restrict__ Wp) {
  const int gid  = blockIdx.x * 256 + threadIdx.x;   // 0..262143, one short8 each
  const int lane = gid & 63;
  const int t    = (gid >> 6) & 15;
  const int cb   = (gid >> 10) & 31;
  const int nb   = gid >> 15;
  const int col  = cb * 16 + (lane & 15);
  const int k    = t * 32 + (lane >> 4) * 8;
  const float* src = W + (size_t)(nb * DOUT + col) * DIN + k;
  f32x4 lo = *(const f32x4*)src;
  f32x4 hi = *(const f32x4*)(src + 4);
  *(short8*)(Wp + (size_t)gid * 8) = cvt8(lo, hi);
}

// Main kernel: NO LDS, NO barriers. 128x128 tile, 4 waves (2x2), each wave a
// 64x64 sub-tile of 4x4 mfma_f32_16x16x32_bf16 fragments. A-fragments load
// direct global->reg (fp32, cvt in-reg); B-fragments are coalesced short8
// from Wp (or scattered fp32 from W if workspace was too small).
template <bool WPREP>
__global__ __launch_bounds__(256, 2) void blocklinear_kernel(
    const float* __restrict__ x, const float* __restrict__ W,
    const short* __restrict__ Wp, const float* __restrict__ bias,
    float* __restrict__ y)
{
  // XCD swizzle (bijective: 2048 % 8 == 0): one nb per XCD; nt innermost so
  // nt-siblings sharing an x panel are co-resident on one XCD's L2.
  const int b       = blockIdx.x;
  const int logical = (b & 7) * 256 + (b >> 3);
  const int nb  = logical >> 8;
  const int rem = logical & 255;
  const int mt  = rem >> 2;
  const int nt  = rem & 3;

  const int tid  = threadIdx.x;
  const int lane = tid & 63;
  const int wid  = tid >> 6;
  const int wr   = wid >> 1;
  const int wc   = wid & 1;
  const int l15  = lane & 15;
  const int k16  = lane >> 4;

  // A: frag m, K-step t -> abase + m*16*NFEAT + t*32  (2x f32x4 per frag)
  const float* abase = x + (size_t)(mt * 128 + wr * 64 + l15) * NFEAT + nb * DIN + k16 * 8;
  // B (WPREP): frag n, step t -> wpbase + n*(16*512) + t*512  (1x short8)
  const short* wpbase = WPREP
      ? Wp + ((size_t)(nb * 32 + nt * 8 + wc * 4) * 16) * 512 + lane * 8
      : nullptr;
  // B (fallback): scattered fp32 from W, same frag pattern as A
  const float* wbase = WPREP
      ? nullptr
      : W + (size_t)nb * DOUT * DIN + (size_t)(nt * 128 + wc * 64 + l15) * DIN + k16 * 8;

  f32x4 acc[4][4];
#pragma unroll
  for (int m = 0; m < 4; ++m)
#pragma unroll
    for (int n = 0; n < 4; ++n)
      acc[m][n] = (f32x4){0.f, 0.f, 0.f, 0.f};

  // two named staging sets (static indexing only)
  f32x4 aL0[4], aH0[4], aL1[4], aH1[4];
  short8 bq0[4], bq1[4];
  f32x4 bL0[4], bH0[4], bL1[4], bH1[4];

#define LOADT(S, t)                                                         \
  {                                                                         \
    _Pragma("unroll")                                                       \
    for (int m = 0; m < 4; ++m) {                                           \
      const float* ap = abase + (size_t)m * 16 * NFEAT + (t) * 32;          \
      aL##S[m] = *(const f32x4*)ap;                                         \
      aH##S[m] = *(const f32x4*)(ap + 4);                                   \
    }                                                                       \
    if constexpr (WPREP) {                                                  \
      _Pragma("unroll")                                                     \
      for (int n = 0; n < 4; ++n)                                           \
        bq##S[n] = *(const short8*)(wpbase + (size_t)n * 16 * 512 + (t) * 512); \
    } else {                                                                \
      _Pragma("unroll")                                                     \
      for (int n = 0; n < 4; ++n) {                                         \
        const float* bp = wbase + (size_t)n * 16 * DIN + (t) * 32;          \
        bL##S[n] = *(const f32x4*)bp;                                       \
        bH##S[n] = *(const f32x4*)(bp + 4);                                 \
      }                                                                     \
    }                                                                       \
  }

#define COMPT(S)                                                            \
  {                                                                         \
    short8 af[4], bf[4];                                                    \
    _Pragma("unroll")                                                       \
    for (int m = 0; m < 4; ++m) af[m] = cvt8(aL##S[m], aH##S[m]);           \
    if constexpr (WPREP) {                                                  \
      _Pragma("unroll")                                                     \
      for (int n = 0; n < 4; ++n) bf[n] = bq##S[n];                         \
    } else {                                                                \
      _Pragma("unroll")                                                     \
      for (int n = 0; n < 4; ++n) bf[n] = cvt8(bL##S[n], bH##S[n]);         \
    }                                                                       \
    _Pragma("unroll")                                                       \
    for (int m = 0; m < 4; ++m)                                             \
      _Pragma("unroll")                                                     \
      for (int n = 0; n < 4; ++n)                                           \
        acc[m][n] = __builtin_amdgcn_mfma_f32_16x16x32_bf16(af[m], bf[n], acc[m][n], 0, 0, 0); \
  }

  LOADT(0, 0);
#pragma unroll
  for (int tt = 0; tt < NT; tt += 2) {
    LOADT(1, tt + 1);                 // always in range (NT even)
    COMPT(0);
    if (tt + 2 < NT) LOADT(0, tt + 2);
    COMPT(1);
  }

  // epilogue: C/D layout col = lane&15, row = (lane>>4)*4 + j  [m89-verified]
  const int col0 = nt * 128 + wc * 64;
  const int row0 = mt * 128 + wr * 64;
  const float* bptr = bias + nb * DOUT + col0;
#pragma unroll
  for (int n = 0; n < 4; ++n) {
    const float bv = bptr[n * 16 + l15];
    const size_t col = (size_t)nb * DOUT + col0 + n * 16 + l15;
#pragma unroll
    for (int m = 0; m < 4; ++m) {
      const int row = row0 + m * 16 + k16 * 4;
      float* yp = y + (size_t)row * NFEAT + col;
#pragma unroll
      for (int j = 0; j < 4; ++j)
        yp[(size_t)j * NFEAT] = acc[m][n][j] + bv;
    }
  }
}

extern "C" void kernel_launch(void* const* d_in, const int* in_sizes, int n_in,
                              void* d_out, int out_size, void* d_ws, size_t ws_size,
                              hipStream_t stream) {
  const float* x  = (const float*)d_in[0];
  const float* W  = (const float*)d_in[1];
  const float* bi = (const float*)d_in[2];
  float* y = (float*)d_out;
  const size_t wp_bytes = (size_t)NBLK * DOUT * DIN * sizeof(short);  // 4 MiB
  const int grid = NBLK * (BATCH / 128) * (DOUT / 128);               // 2048

  if (ws_size >= wp_bytes) {
    short* Wp = (short*)d_ws;
    wprep_kernel<<<(NBLK * DOUT * DIN / 8) / 256, 256, 0, stream>>>(W, Wp);
    blocklinear_kernel<true><<<grid, 256, 0, stream>>>(x, W, Wp, bi, y);
  } else {
    blocklinear_kernel<false><<<grid, 256, 0, stream>>>(x, W, nullptr, bi, y);
  }
}

// Round 4
// 97.181 us; speedup vs baseline: 1.8562x; 1.8562x over previous
//
#include <hip/hip_runtime.h>
#include <hip/hip_bf16.h>

#define NBLK 8
#define DIN 512
#define DOUT 512
#define NFEAT 4096      // NBLK * DIN
#define BATCH 8192
#define NT 16           // DIN / 32 K-steps
#define TSZ (128 * 32)  // shorts per A LDS buffer (8 KB)

typedef __attribute__((ext_vector_type(8))) short short8;
typedef __attribute__((ext_vector_type(4))) float f32x4;

static __device__ __forceinline__ short f2bf16(float f) {
  __bf16 h = (__bf16)f;               // RNE; compiler packs pairs into v_cvt_pk_bf16_f32
  return __builtin_bit_cast(short, h);
}

static __device__ __forceinline__ short8 cvt8(f32x4 lo, f32x4 hi) {
  short8 o;
  o[0] = f2bf16(lo[0]); o[1] = f2bf16(lo[1]); o[2] = f2bf16(lo[2]); o[3] = f2bf16(lo[3]);
  o[4] = f2bf16(hi[0]); o[5] = f2bf16(hi[1]); o[6] = f2bf16(hi[2]); o[7] = f2bf16(hi[3]);
  return o;
}

// raw barrier: lgkmcnt(0) for ds_write visibility, NO vmcnt drain (global
// loads stay in flight across it — the whole point of the pipeline).
#define PIPE_BARRIER()                                      \
  do {                                                      \
    __builtin_amdgcn_sched_barrier(0);                      \
    asm volatile("s_waitcnt lgkmcnt(0)" ::: "memory");      \
    __builtin_amdgcn_s_barrier();                           \
    __builtin_amdgcn_sched_barrier(0);                      \
  } while (0)

// Pre-pass: W [8][512][512] fp32 -> Wp fragment-major bf16; the main kernel's
// B-fragment becomes one coalesced short8 (1 KB/wave-instr from L2).
//   Wp[(((nb*32 + cb)*16 + t)*64 + lane)*8 + j]
//     = bf16( W[nb][cb*16 + (lane&15)][t*32 + (lane>>4)*8 + j] )
__global__ __launch_bounds__(256) void wprep_kernel(const float* __restrict__ W,
                                                    short* __restrict__ Wp) {
  const int gid  = blockIdx.x * 256 + threadIdx.x;
  const int lane = gid & 63;
  const int t    = (gid >> 6) & 15;
  const int cb   = (gid >> 10) & 31;
  const int nb   = gid >> 15;
  const int col  = cb * 16 + (lane & 15);
  const int k    = t * 32 + (lane >> 4) * 8;
  const float* src = W + (size_t)(nb * DOUT + col) * DIN + k;
  f32x4 lo = *(const f32x4*)src;
  f32x4 hi = *(const f32x4*)(src + 4);
  *(short8*)(Wp + (size_t)gid * 8) = cvt8(lo, hi);
}

// Main: 128x128 tile, 4 waves (2x2). A (x, fp32) reg-staged -> bf16 -> LDS
// triple-buffer, distance-2 prefetch, one raw barrier per K-step. B (W)
// direct global->reg from Wp, distance-2, never blocked by barriers.
template <bool WPREP>
__global__ __launch_bounds__(256, 3) void blocklinear_kernel(
    const float* __restrict__ x, const float* __restrict__ W,
    const short* __restrict__ Wp, const float* __restrict__ bias,
    float* __restrict__ y)
{
  // XCD swizzle (bijective: 2048 % 8 == 0): one nb per XCD; nt innermost so
  // the 4 nt-siblings sharing an x panel are co-resident on one XCD's L2.
  const int b       = blockIdx.x;
  const int logical = (b & 7) * 256 + (b >> 3);
  const int nb  = logical >> 8;
  const int rem = logical & 255;
  const int mt  = rem >> 2;
  const int nt  = rem & 3;

  const int tid  = threadIdx.x;
  const int lane = tid & 63;
  const int wid  = tid >> 6;
  const int wr   = wid >> 1;
  const int wc   = wid & 1;
  const int l15  = lane & 15;
  const int k16  = lane >> 4;

  __shared__ short Abuf[3][TSZ];   // 24 KB total

  // --- A staging (write side): thread t covers row r, floats [h*16, h*16+16).
  // Swizzle chunk' = chunk ^ ((row>>1)&3) (16B chunks) -> both ds_write_b128
  // and ds_read_b128 hit the 8-phase conflict-free minimum (R2: 0 conflicts).
  const int r = tid >> 1;
  const int h = tid & 1;
  const int q = (r >> 1) & 3;
  const int wa0 = r * 32 + (((2 * h)     ^ q) * 8);
  const int wa1 = r * 32 + (((2 * h + 1) ^ q) * 8);
  const float* ap = x + (size_t)(mt * 128 + r) * NFEAT + nb * DIN + h * 16;

  // --- A fragment read offsets (per m, compile-time unrolled)
  int ra[4];
#pragma unroll
  for (int m = 0; m < 4; ++m) {
    const int row = wr * 64 + m * 16 + l15;
    ra[m] = row * 32 + ((k16 ^ ((row >> 1) & 3)) * 8);
  }

  // --- B pointers
  const short* wpbase = WPREP
      ? Wp + ((size_t)(nb * 32 + nt * 8 + wc * 4) * 16) * 512 + lane * 8
      : nullptr;
  const float* wbase = WPREP
      ? nullptr
      : W + (size_t)nb * DOUT * DIN + (size_t)(nt * 128 + wc * 64 + l15) * DIN + k16 * 8;

  f32x4 acc[4][4];
#pragma unroll
  for (int m = 0; m < 4; ++m)
#pragma unroll
    for (int n = 0; n < 4; ++n)
      acc[m][n] = (f32x4){0.f, 0.f, 0.f, 0.f};

  // staging register sets (named -> static indexing, rule #20)
  f32x4 a0[4], a1[4];
  short8 bq0[4], bq1[4];
  f32x4 bL0[4], bH0[4], bL1[4], bH1[4];   // fallback only

#define LOAD_A(S, t)                                                        \
  {                                                                         \
    _Pragma("unroll")                                                       \
    for (int i = 0; i < 4; ++i)                                             \
      a##S[i] = *(const f32x4*)(ap + (t) * 32 + i * 4);                     \
  }

#define LOAD_B(S, t)                                                        \
  {                                                                         \
    if constexpr (WPREP) {                                                  \
      _Pragma("unroll")                                                     \
      for (int n = 0; n < 4; ++n)                                           \
        bq##S[n] = *(const short8*)(wpbase + (size_t)n * 16 * 512 + (t) * 512); \
    } else {                                                                \
      _Pragma("unroll")                                                     \
      for (int n = 0; n < 4; ++n) {                                         \
        const float* bp = wbase + (size_t)n * 16 * DIN + (t) * 32;          \
        bL##S[n] = *(const f32x4*)bp;                                       \
        bH##S[n] = *(const f32x4*)(bp + 4);                                 \
      }                                                                     \
    }                                                                       \
  }

#define WRITE_A(S, bp)                                                      \
  {                                                                         \
    *(short8*)((bp) + wa0) = cvt8(a##S[0], a##S[1]);                        \
    *(short8*)((bp) + wa1) = cvt8(a##S[2], a##S[3]);                        \
  }

#define COMPUTE(bufidx, S)                                                  \
  {                                                                         \
    const short* lb = &Abuf[bufidx][0];                                     \
    short8 af[4], bf[4];                                                    \
    _Pragma("unroll")                                                       \
    for (int m = 0; m < 4; ++m) af[m] = *(const short8*)(lb + ra[m]);       \
    if constexpr (WPREP) {                                                  \
      _Pragma("unroll")                                                     \
      for (int n = 0; n < 4; ++n) bf[n] = bq##S[n];                         \
    } else {                                                                \
      _Pragma("unroll")                                                     \
      for (int n = 0; n < 4; ++n) bf[n] = cvt8(bL##S[n], bH##S[n]);         \
    }                                                                       \
    __builtin_amdgcn_s_setprio(1);                                          \
    _Pragma("unroll")                                                       \
    for (int m = 0; m < 4; ++m)                                             \
      _Pragma("unroll")                                                     \
      for (int n = 0; n < 4; ++n)                                           \
        acc[m][n] = __builtin_amdgcn_mfma_f32_16x16x32_bf16(af[m], bf[n], acc[m][n], 0, 0, 0); \
    __builtin_amdgcn_s_setprio(0);                                          \
  }

  // prologue: sets 0/1 <- tiles 0/1; tile 0 staged into buf 0
  LOAD_A(0, 0); LOAD_B(0, 0);
  LOAD_A(1, 1); LOAD_B(1, 1);
  WRITE_A(0, &Abuf[0][0]);

  // steady state, fully unrolled (8x two-step bodies). Iter t:
  //   issue A(t+2) -> set t&1 (freed: A(t) written last iter)
  //   write A(t+1) from set (t+1)&1 (auto-counted vmcnt wait)
  //   raw barrier (lgkm only)
  //   compute(t) from Abuf[t%3] with B(t) regs
  //   issue B(t+2) -> set t&1 (freed: B(t) just consumed)
#pragma unroll
  for (int tt = 0; tt < NT; tt += 2) {
    // even t = tt  (S=0)
    if (tt + 2 < NT) LOAD_A(0, tt + 2);
    WRITE_A(1, &Abuf[(tt + 1) % 3][0]);          // tt+1 <= 15 always
    PIPE_BARRIER();
    COMPUTE(tt % 3, 0);
    if (tt + 2 < NT) LOAD_B(0, tt + 2);
    // odd t = tt+1  (S=1)
    if (tt + 3 < NT) LOAD_A(1, tt + 3);
    if (tt + 2 < NT) WRITE_A(0, &Abuf[(tt + 2) % 3][0]);
    PIPE_BARRIER();
    COMPUTE((tt + 1) % 3, 1);
    if (tt + 3 < NT) LOAD_B(1, tt + 3);
  }

  // epilogue: C/D layout col = lane&15, row = (lane>>4)*4 + j  [m89-verified]
  const int col0 = nt * 128 + wc * 64;
  const int row0 = mt * 128 + wr * 64;
  const float* bptr = bias + nb * DOUT + col0;
#pragma unroll
  for (int n = 0; n < 4; ++n) {
    const float bv = bptr[n * 16 + l15];
    const size_t col = (size_t)nb * DOUT + col0 + n * 16 + l15;
#pragma unroll
    for (int m = 0; m < 4; ++m) {
      const int row = row0 + m * 16 + k16 * 4;
      float* yp = y + (size_t)row * NFEAT + col;
#pragma unroll
      for (int j = 0; j < 4; ++j)
        yp[(size_t)j * NFEAT] = acc[m][n][j] + bv;
    }
  }
}

extern "C" void kernel_launch(void* const* d_in, const int* in_sizes, int n_in,
                              void* d_out, int out_size, void* d_ws, size_t ws_size,
                              hipStream_t stream) {
  const float* x  = (const float*)d_in[0];
  const float* W  = (const float*)d_in[1];
  const float* bi = (const float*)d_in[2];
  float* y = (float*)d_out;
  const size_t wp_bytes = (size_t)NBLK * DOUT * DIN * sizeof(short);  // 4 MiB
  const int grid = NBLK * (BATCH / 128) * (DOUT / 128);               // 2048

  if (ws_size >= wp_bytes) {
    short* Wp = (short*)d_ws;
    wprep_kernel<<<(NBLK * DOUT * DIN / 8) / 256, 256, 0, stream>>>(W, Wp);
    blocklinear_kernel<true><<<grid, 256, 0, stream>>>(x, W, Wp, bi, y);
  } else {
    blocklinear_kernel<false><<<grid, 256, 0, stream>>>(x, W, nullptr, bi, y);
  }
}

// Round 5
// 86.561 us; speedup vs baseline: 2.0840x; 1.1227x over previous
//
#include <hip/hip_runtime.h>
#include <hip/hip_bf16.h>

#define NBLK 8
#define DIN 512
#define DOUT 512
#define NFEAT 4096      // NBLK * DIN
#define BATCH 8192
#define NT 16           // DIN / 32 K-steps
#define ABUF_F 4096     // floats per A buffer: 128 rows * 32 k (16 KB)

typedef __attribute__((ext_vector_type(8))) short short8;
typedef __attribute__((ext_vector_type(4))) float f32x4;

static __device__ __forceinline__ short f2bf16(float f) {
  __bf16 h = (__bf16)f;               // RNE; compiler packs pairs into v_cvt_pk_bf16_f32
  return __builtin_bit_cast(short, h);
}

static __device__ __forceinline__ short8 cvt8(f32x4 lo, f32x4 hi) {
  short8 o;
  o[0] = f2bf16(lo[0]); o[1] = f2bf16(lo[1]); o[2] = f2bf16(lo[2]); o[3] = f2bf16(lo[3]);
  o[4] = f2bf16(hi[0]); o[5] = f2bf16(hi[1]); o[6] = f2bf16(hi[2]); o[7] = f2bf16(hi[3]);
  return o;
}

// global -> LDS DMA, 16 B/lane, lands at lds_base + lane*16 (linear dest).
static __device__ __forceinline__ void gload_lds16(const float* g, float* l) {
  __builtin_amdgcn_global_load_lds(
      (const __attribute__((address_space(1))) void*)g,
      (__attribute__((address_space(3))) void*)l, 16, 0, 0);
}

// Pre-pass: W [8][512][512] fp32 -> Wp fragment-major bf16; main kernel's
// B-fragment = one coalesced short8 (1 KB/wave-instr, L2-resident slices).
__global__ __launch_bounds__(256) void wprep_kernel(const float* __restrict__ W,
                                                    short* __restrict__ Wp) {
  const int gid  = blockIdx.x * 256 + threadIdx.x;
  const int lane = gid & 63;
  const int t    = (gid >> 6) & 15;
  const int cb   = (gid >> 10) & 31;
  const int nb   = gid >> 15;
  const int col  = cb * 16 + (lane & 15);
  const int k    = t * 32 + (lane >> 4) * 8;
  const float* src = W + (size_t)(nb * DOUT + col) * DIN + k;
  f32x4 lo = *(const f32x4*)src;
  f32x4 hi = *(const f32x4*)(src + 4);
  *(short8*)(Wp + (size_t)gid * 8) = cvt8(lo, hi);
}

// Main: 128x128 tile, 4 waves (2x2), wave = 64x64 (4x4 frags).
// A (x, fp32) staged fp32-in-LDS via global_load_lds (3 bufs, distance-2,
// pre-swizzled source chunk c^(row&7), linear dest, swizzled read -> 0-conflict).
// Conversion fp32->bf16 happens at fragment read (VALU idle anyway).
// B (Wp bf16) direct global->reg, distance-2, 2 named sets.
// Per step: counted vmcnt (never 0 mid-loop) + raw s_barrier. No ds_write,
// no lgkm coupling, no reg-staging round trip.
template <bool WPREP>
__global__ __launch_bounds__(256, 3) void blocklinear_kernel(
    const float* __restrict__ x, const float* __restrict__ W,
    const short* __restrict__ Wp, const float* __restrict__ bias,
    float* __restrict__ y)
{
  // XCD swizzle (bijective: 2048 % 8 == 0): one nb per XCD, nt innermost.
  const int b       = blockIdx.x;
  const int logical = (b & 7) * 256 + (b >> 3);
  const int nb  = logical >> 8;
  const int rem = logical & 255;
  const int mt  = rem >> 2;
  const int nt  = rem & 3;

  const int tid  = threadIdx.x;
  const int lane = tid & 63;
  const int w    = tid >> 6;   // wave 0..3
  const int wr   = w >> 1;
  const int wc   = w & 1;
  const int l15  = lane & 15;
  const int k16  = lane >> 4;

  __shared__ float Abuf[3][ABUF_F];   // 48 KB

  // --- A staging (DMA): wave w, sub-instr i covers rows [w*32+i*8, +8).
  // lane l -> row r = r0 + (l>>3), chunk c = l&7 (16 B). Linear LDS dest;
  // SOURCE pre-swizzled: reads data chunk c ^ (r&7).
  const int l8 = lane >> 3;
  const int c  = lane & 7;
  const float* asrc[4];
#pragma unroll
  for (int i = 0; i < 4; ++i) {
    const int r  = w * 32 + i * 8 + l8;          // row in tile
    const int cs = c ^ (r & 7);                  // swizzled source chunk
    asrc[i] = x + (size_t)(mt * 128 + r) * NFEAT + nb * DIN + cs * 4;
  }
  // wave-uniform LDS dest offsets (floats): (w*32 + i*8) * 32

#define STAGE_A(bufidx, t)                                                  \
  {                                                                         \
    _Pragma("unroll")                                                       \
    for (int i = 0; i < 4; ++i)                                             \
      gload_lds16(asrc[i] + (t) * 32, &Abuf[bufidx][w * 1024 + i * 256]);   \
  }

  // --- A fragment read offsets (swizzled): data chunk cw read at cw^(row&7)
  int ra_lo[4], ra_hi[4];
#pragma unroll
  for (int m = 0; m < 4; ++m) {
    const int row = wr * 64 + m * 16 + l15;
    const int r7  = row & 7;
    ra_lo[m] = row * 32 + (((2 * k16)     ^ r7) * 4);
    ra_hi[m] = row * 32 + (((2 * k16 + 1) ^ r7) * 4);
  }

  // --- B pointers
  const short* wpbase = WPREP
      ? Wp + ((size_t)(nb * 32 + nt * 8 + wc * 4) * 16) * 512 + lane * 8
      : nullptr;
  const float* wbase = WPREP
      ? nullptr
      : W + (size_t)nb * DOUT * DIN + (size_t)(nt * 128 + wc * 64 + l15) * DIN + k16 * 8;

  f32x4 acc[4][4];
#pragma unroll
  for (int m = 0; m < 4; ++m)
#pragma unroll
    for (int n = 0; n < 4; ++n)
      acc[m][n] = (f32x4){0.f, 0.f, 0.f, 0.f};

  short8 bq0[4], bq1[4];
  f32x4 bL0[4], bH0[4], bL1[4], bH1[4];   // fallback only

#define LOAD_B(S, t)                                                        \
  {                                                                         \
    if constexpr (WPREP) {                                                  \
      _Pragma("unroll")                                                     \
      for (int n = 0; n < 4; ++n)                                           \
        bq##S[n] = *(const short8*)(wpbase + (size_t)n * 16 * 512 + (t) * 512); \
    } else {                                                                \
      _Pragma("unroll")                                                     \
      for (int n = 0; n < 4; ++n) {                                         \
        const float* bp = wbase + (size_t)n * 16 * DIN + (t) * 32;          \
        bL##S[n] = *(const f32x4*)bp;                                       \
        bH##S[n] = *(const f32x4*)(bp + 4);                                 \
      }                                                                     \
    }                                                                       \
  }

#define COMPUTE(bufidx, S)                                                  \
  {                                                                         \
    const float* lb = &Abuf[bufidx][0];                                     \
    short8 af[4], bf[4];                                                    \
    _Pragma("unroll")                                                       \
    for (int m = 0; m < 4; ++m) {                                           \
      f32x4 lo = *(const f32x4*)(lb + ra_lo[m]);                            \
      f32x4 hi = *(const f32x4*)(lb + ra_hi[m]);                            \
      af[m] = cvt8(lo, hi);                                                 \
    }                                                                       \
    if constexpr (WPREP) {                                                  \
      _Pragma("unroll")                                                     \
      for (int n = 0; n < 4; ++n) bf[n] = bq##S[n];                         \
    } else {                                                                \
      _Pragma("unroll")                                                     \
      for (int n = 0; n < 4; ++n) bf[n] = cvt8(bL##S[n], bH##S[n]);         \
    }                                                                       \
    __builtin_amdgcn_s_setprio(1);                                          \
    _Pragma("unroll")                                                       \
    for (int m = 0; m < 4; ++m)                                             \
      _Pragma("unroll")                                                     \
      for (int n = 0; n < 4; ++n)                                           \
        acc[m][n] = __builtin_amdgcn_mfma_f32_16x16x32_bf16(af[m], bf[n], acc[m][n], 0, 0, 0); \
    __builtin_amdgcn_s_setprio(0);                                          \
  }

  // Step t: issue A(t+2) DMA into buf (t+2)%3 (= buf read at t-1, barrier-safe);
  // compute buf t%3 with B-set t&1; issue B(t+2) into freed set; counted
  // vmcnt: 8 newer ops (4 A-DMA + 4 B) stay in flight, A(t+1)/B(t+1) land.
#define STEP(t, S)                                                          \
  {                                                                         \
    if ((t) + 2 < NT) STAGE_A(((t) + 2) % 3, (t) + 2);                      \
    COMPUTE((t) % 3, S);                                                    \
    if ((t) + 2 < NT) LOAD_B(S, (t) + 2);                                   \
    __builtin_amdgcn_sched_barrier(0);                                      \
    if ((t) + 2 < NT) {                                                     \
      if constexpr (WPREP) asm volatile("s_waitcnt vmcnt(8)" ::: "memory"); \
      else                 asm volatile("s_waitcnt vmcnt(12)" ::: "memory");\
    } else {                                                                \
      asm volatile("s_waitcnt vmcnt(0)" ::: "memory");                      \
    }                                                                       \
    __builtin_amdgcn_s_barrier();                                           \
    __builtin_amdgcn_sched_barrier(0);                                      \
  }

  // prologue: A(0)->buf0, A(1)->buf1, B(0)->set0, B(1)->set1; wait A(0) only
  STAGE_A(0, 0);
  STAGE_A(1, 1);
  LOAD_B(0, 0);
  LOAD_B(1, 1);
  __builtin_amdgcn_sched_barrier(0);
  if constexpr (WPREP) asm volatile("s_waitcnt vmcnt(12)" ::: "memory");
  else                 asm volatile("s_waitcnt vmcnt(20)" ::: "memory");
  __builtin_amdgcn_s_barrier();
  __builtin_amdgcn_sched_barrier(0);

#pragma unroll
  for (int tt = 0; tt < NT; tt += 2) {
    STEP(tt, 0);
    STEP(tt + 1, 1);
  }

  // epilogue: C/D layout col = lane&15, row = (lane>>4)*4 + j  [m89-verified]
  const int col0 = nt * 128 + wc * 64;
  const int row0 = mt * 128 + wr * 64;
  const float* bptr = bias + nb * DOUT + col0;
#pragma unroll
  for (int n = 0; n < 4; ++n) {
    const float bv = bptr[n * 16 + l15];
    const size_t col = (size_t)nb * DOUT + col0 + n * 16 + l15;
#pragma unroll
    for (int m = 0; m < 4; ++m) {
      const int row = row0 + m * 16 + k16 * 4;
      float* yp = y + (size_t)row * NFEAT + col;
#pragma unroll
      for (int j = 0; j < 4; ++j)
        yp[(size_t)j * NFEAT] = acc[m][n][j] + bv;
    }
  }
}

extern "C" void kernel_launch(void* const* d_in, const int* in_sizes, int n_in,
                              void* d_out, int out_size, void* d_ws, size_t ws_size,
                              hipStream_t stream) {
  const float* x  = (const float*)d_in[0];
  const float* W  = (const float*)d_in[1];
  const float* bi = (const float*)d_in[2];
  float* y = (float*)d_out;
  const size_t wp_bytes = (size_t)NBLK * DOUT * DIN * sizeof(short);  // 4 MiB
  const int grid = NBLK * (BATCH / 128) * (DOUT / 128);               // 2048

  if (ws_size >= wp_bytes) {
    short* Wp = (short*)d_ws;
    wprep_kernel<<<(NBLK * DOUT * DIN / 8) / 256, 256, 0, stream>>>(W, Wp);
    blocklinear_kernel<true><<<grid, 256, 0, stream>>>(x, W, Wp, bi, y);
  } else {
    blocklinear_kernel<false><<<grid, 256, 0, stream>>>(x, W, nullptr, bi, y);
  }
}

// Round 6
// 84.296 us; speedup vs baseline: 2.1399x; 1.0269x over previous
//
#include <hip/hip_runtime.h>
#include <hip/hip_bf16.h>

#define NBLK 8
#define DIN 512
#define DOUT 512
#define NFEAT 4096      // NBLK * DIN
#define BATCH 8192
#define NT 16           // DIN / 32 K-steps
#define BM 256
#define BN 128

typedef __attribute__((ext_vector_type(8))) short short8;
typedef __attribute__((ext_vector_type(4))) float f32x4;

static __device__ __forceinline__ short f2bf16(float f) {
  __bf16 h = (__bf16)f;               // RNE; compiler packs into v_cvt_pk_bf16_f32
  return __builtin_bit_cast(short, h);
}

static __device__ __forceinline__ short8 cvt8(f32x4 lo, f32x4 hi) {
  short8 o;
  o[0] = f2bf16(lo[0]); o[1] = f2bf16(lo[1]); o[2] = f2bf16(lo[2]); o[3] = f2bf16(lo[3]);
  o[4] = f2bf16(hi[0]); o[5] = f2bf16(hi[1]); o[6] = f2bf16(hi[2]); o[7] = f2bf16(hi[3]);
  return o;
}

static __device__ __forceinline__ void gload_lds16(const float* g, float* l) {
  __builtin_amdgcn_global_load_lds(
      (const __attribute__((address_space(1))) void*)g,
      (__attribute__((address_space(3))) void*)l, 16, 0, 0);
}

// Pre-pass: W [8][512][512] fp32 -> Wp fragment-major bf16 (one coalesced
// short8 per B-fragment in the main kernel; Wp slice per nb = 512 KB, L2-hot).
__global__ __launch_bounds__(256) void wprep_kernel(const float* __restrict__ W,
                                                    short* __restrict__ Wp) {
  const int gid  = blockIdx.x * 256 + threadIdx.x;
  const int lane = gid & 63;
  const int t    = (gid >> 6) & 15;
  const int cb   = (gid >> 10) & 31;
  const int nb   = gid >> 15;
  const int col  = cb * 16 + (lane & 15);
  const int k    = t * 32 + (lane >> 4) * 8;
  const float* src = W + (size_t)(nb * DOUT + col) * DIN + k;
  f32x4 lo = *(const f32x4*)src;
  f32x4 hi = *(const f32x4*)(src + 4);
  *(short8*)(Wp + (size_t)gid * 8) = cvt8(lo, hi);
}

// Main kernel: 256x128 block, 4 M-STACKED waves (wave w owns rows
// [w*64, w*64+64), all 128 cols; 4x8 frags = 32 MFMA/step, acc = 128 regs).
// A is WAVE-PRIVATE: each wave DMAs its own 64 rows into its own LDS region
// and only it reads them -> NO s_barrier anywhere. The DMA->ds_read
// dependency is a per-wave counted vmcnt (16 steady, never drained).
// Waves free-run: no convoy on the shared LDS pipe.
// Swizzle: DMA dest linear; source chunk pre-XOR'd (l&7)^(l>>3); read applies
// slot = chunk ^ (row&7) -> both sides at the b128 bank minimum.
template <bool WPREP>
__global__ __launch_bounds__(256, 2) void blocklinear_kernel(
    const float* __restrict__ x, const float* __restrict__ W,
    const short* __restrict__ Wp, const float* __restrict__ bias,
    float* __restrict__ y)
{
  // XCD swizzle (bijective: 1024 % 8 == 0): one nb per XCD, nt innermost
  // (4 nt-siblings share an x M-panel; panel 512 KB + Wp slice 512 KB fit L2).
  const int b       = blockIdx.x;
  const int logical = (b & 7) * 128 + (b >> 3);
  const int nb  = logical >> 7;
  const int rem = logical & 127;
  const int mt  = rem >> 2;    // 0..31
  const int nt  = rem & 3;     // 0..3

  const int tid  = threadIdx.x;
  const int lane = tid & 63;
  const int w    = tid >> 6;   // wave 0..3 (M-stacked)
  const int l15  = lane & 15;
  const int k16  = lane >> 4;

  __shared__ __align__(16) float Abuf[2][4][2048];   // [buf][wave][64 rows x 32 f] = 64 KB

  // --- A DMA: instr i (0..7) covers wave-rows [i*8, i*8+8); lane l -> row
  // i*8 + (l>>3), dest chunk l&7 (linear). Source reads data chunk
  // (l&7)^(l>>3) = (l&7)^(row&7)  -> stored slot s holds data chunk s^(row&7).
  const int l8 = lane >> 3;
  const int c  = lane & 7;
  const float* asrc[8];
#pragma unroll
  for (int i = 0; i < 8; ++i) {
    const int rl = i * 8 + l8;                     // row within wave region
    const int gr = mt * BM + w * 64 + rl;          // global x row
    asrc[i] = x + (size_t)gr * NFEAT + nb * DIN + ((c ^ l8) << 2);
  }

#define STAGE_A(bufidx, t)                                                  \
  {                                                                         \
    _Pragma("unroll")                                                       \
    for (int i = 0; i < 8; ++i)                                             \
      gload_lds16(asrc[i] + (t) * 32, &Abuf[bufidx][w][i * 256]);           \
  }

  // --- A fragment read offsets (floats), m-invariant parts:
  // addr = row_local*32 + slot*4, row_local = m*16 + l15,
  // slot_lo = (2k16)^(l15&7), slot_hi = (2k16+1)^(l15&7)
  const int ra_lo = l15 * 32 + (((2 * k16)     ^ (l15 & 7)) << 2);
  const int ra_hi = l15 * 32 + (((2 * k16 + 1) ^ (l15 & 7)) << 2);

  // --- B pointers (wave reads all 8 col-frags of the 128-col tile)
  const short* wpbase = WPREP
      ? Wp + ((size_t)(nb * 32 + nt * 8) * 16) * 512 + lane * 8
      : nullptr;
  const float* wbase = WPREP
      ? nullptr
      : W + (size_t)nb * DOUT * DIN + (size_t)(nt * BN + l15) * DIN + k16 * 8;

  f32x4 acc[4][8];
#pragma unroll
  for (int m = 0; m < 4; ++m)
#pragma unroll
    for (int n = 0; n < 8; ++n)
      acc[m][n] = (f32x4){0.f, 0.f, 0.f, 0.f};

  short8 bq[8];
  f32x4 bL[8], bH[8];   // fallback only

#define LOAD_B(t)                                                           \
  {                                                                         \
    if constexpr (WPREP) {                                                  \
      _Pragma("unroll")                                                     \
      for (int n = 0; n < 8; ++n)                                           \
        bq[n] = *(const short8*)(wpbase + (size_t)n * 8192 + (t) * 512);    \
    } else {                                                                \
      _Pragma("unroll")                                                     \
      for (int n = 0; n < 8; ++n) {                                         \
        const float* bp = wbase + (size_t)n * 16 * DIN + (t) * 32;          \
        bL[n] = *(const f32x4*)bp;                                          \
        bH[n] = *(const f32x4*)(bp + 4);                                    \
      }                                                                     \
    }                                                                       \
  }

#define COMPUTE(bufidx)                                                     \
  {                                                                         \
    const float* lb = &Abuf[bufidx][w][0];                                  \
    short8 af[4], bf[8];                                                    \
    _Pragma("unroll")                                                       \
    for (int m = 0; m < 4; ++m) {                                           \
      f32x4 lo = *(const f32x4*)(lb + m * 512 + ra_lo);                     \
      f32x4 hi = *(const f32x4*)(lb + m * 512 + ra_hi);                     \
      af[m] = cvt8(lo, hi);                                                 \
    }                                                                       \
    if constexpr (WPREP) {                                                  \
      _Pragma("unroll")                                                     \
      for (int n = 0; n < 8; ++n) bf[n] = bq[n];                            \
    } else {                                                                \
      _Pragma("unroll")                                                     \
      for (int n = 0; n < 8; ++n) bf[n] = cvt8(bL[n], bH[n]);               \
    }                                                                       \
    __builtin_amdgcn_s_setprio(1);                                          \
    _Pragma("unroll")                                                       \
    for (int m = 0; m < 4; ++m)                                             \
      _Pragma("unroll")                                                     \
      for (int n = 0; n < 8; ++n)                                           \
        acc[m][n] = __builtin_amdgcn_mfma_f32_16x16x32_bf16(af[m], bf[n], acc[m][n], 0, 0, 0); \
    __builtin_amdgcn_s_setprio(0);                                          \
  }

  // Step t: stage A(t+1) (distance-1, ~1 step of cover); wait A(t) via
  // counted vmcnt (outstanding after = B(t) 8 + A(t+1) 8 = 16; in-order
  // retire => oldest-8 = A(t) landed); compute; issue B(t+1) post-MFMA
  // (compiler auto-waits bq at next step's MFMA). No barriers.
#define STEP(t, VMC)                                                        \
  {                                                                         \
    if ((t) + 1 < NT) STAGE_A(((t) + 1) & 1, (t) + 1);                      \
    __builtin_amdgcn_sched_barrier(0);                                      \
    asm volatile("s_waitcnt vmcnt(" #VMC ")" ::: "memory");                 \
    __builtin_amdgcn_sched_barrier(0);                                      \
    COMPUTE((t) & 1);                                                       \
    if ((t) + 1 < NT) LOAD_B((t) + 1);                                      \
  }

  STAGE_A(0, 0);
  LOAD_B(0);

  STEP(0, 16)  STEP(1, 16)  STEP(2, 16)  STEP(3, 16)
  STEP(4, 16)  STEP(5, 16)  STEP(6, 16)  STEP(7, 16)
  STEP(8, 16)  STEP(9, 16)  STEP(10, 16) STEP(11, 16)
  STEP(12, 16) STEP(13, 16) STEP(14, 16) STEP(15, 8)

  // epilogue: C/D layout col = lane&15, row = (lane>>4)*4 + j  [m89-verified]
  const int col0 = nt * BN;
  const int row0 = mt * BM + w * 64;
  const float* bptr = bias + nb * DOUT + col0;
#pragma unroll
  for (int n = 0; n < 8; ++n) {
    const float bv = bptr[n * 16 + l15];
    const size_t col = (size_t)nb * DOUT + col0 + n * 16 + l15;
#pragma unroll
    for (int m = 0; m < 4; ++m) {
      const int row = row0 + m * 16 + k16 * 4;
      float* yp = y + (size_t)row * NFEAT + col;
#pragma unroll
      for (int j = 0; j < 4; ++j)
        yp[(size_t)j * NFEAT] = acc[m][n][j] + bv;
    }
  }
}

extern "C" void kernel_launch(void* const* d_in, const int* in_sizes, int n_in,
                              void* d_out, int out_size, void* d_ws, size_t ws_size,
                              hipStream_t stream) {
  const float* x  = (const float*)d_in[0];
  const float* W  = (const float*)d_in[1];
  const float* bi = (const float*)d_in[2];
  float* y = (float*)d_out;
  const size_t wp_bytes = (size_t)NBLK * DOUT * DIN * sizeof(short);  // 4 MiB
  const int grid = NBLK * (BATCH / BM) * (DOUT / BN);                 // 1024

  if (ws_size >= wp_bytes) {
    short* Wp = (short*)d_ws;
    wprep_kernel<<<(NBLK * DOUT * DIN / 8) / 256, 256, 0, stream>>>(W, Wp);
    blocklinear_kernel<true><<<grid, 256, 0, stream>>>(x, W, Wp, bi, y);
  } else {
    blocklinear_kernel<false><<<grid, 256, 0, stream>>>(x, W, nullptr, bi, y);
  }
}

// Round 7
// 77.436 us; speedup vs baseline: 2.3295x; 1.0886x over previous
//
#include <hip/hip_runtime.h>
#include <hip/hip_bf16.h>

#define NBLK 8
#define DIN 512
#define DOUT 512
#define NFEAT 4096      // NBLK * DIN
#define BATCH 8192
#define NT 16           // DIN / 32 K-steps
#define BM 256
#define BN 256

typedef __attribute__((ext_vector_type(8))) short short8;
typedef __attribute__((ext_vector_type(4))) float f32x4;

static __device__ __forceinline__ short f2bf16(float f) {
  __bf16 h = (__bf16)f;               // RNE; compiler packs into v_cvt_pk_bf16_f32
  return __builtin_bit_cast(short, h);
}

static __device__ __forceinline__ short8 cvt8(f32x4 lo, f32x4 hi) {
  short8 o;
  o[0] = f2bf16(lo[0]); o[1] = f2bf16(lo[1]); o[2] = f2bf16(lo[2]); o[3] = f2bf16(lo[3]);
  o[4] = f2bf16(hi[0]); o[5] = f2bf16(hi[1]); o[6] = f2bf16(hi[2]); o[7] = f2bf16(hi[3]);
  return o;
}

static __device__ __forceinline__ void gload_lds16(const void* g, void* l) {
  __builtin_amdgcn_global_load_lds(
      (const __attribute__((address_space(1))) void*)g,
      (__attribute__((address_space(3))) void*)l, 16, 0, 0);
}

// Pre-pass: W [8][512][512] fp32 -> Wp fragment-major bf16. Chunk (nb,cb,t)
// is 1 KB contiguous: lane l holds col cb*16+(l&15), k = t*32+(l>>4)*8.
__global__ __launch_bounds__(256) void wprep_kernel(const float* __restrict__ W,
                                                    short* __restrict__ Wp) {
  const int gid  = blockIdx.x * 256 + threadIdx.x;
  const int lane = gid & 63;
  const int t    = (gid >> 6) & 15;
  const int cb   = (gid >> 10) & 31;
  const int nb   = gid >> 15;
  const int col  = cb * 16 + (lane & 15);
  const int k    = t * 32 + (lane >> 4) * 8;
  const float* src = W + (size_t)(nb * DOUT + col) * DIN + k;
  f32x4 lo = *(const f32x4*)src;
  f32x4 hi = *(const f32x4*)(src + 4);
  *(short8*)(Wp + (size_t)gid * 8) = cvt8(lo, hi);
}

// Main: 256x256 block, 512 threads, 8 waves = 4 M-rows x 2 N-halves,
// wave tile 64x128 (4x8 frags, 32 MFMA/step). TRAFFIC-MINIMIZED:
//   A (x fp32): staged once per block per step via global_load_lds
//     (268 MB total, was 536) — swizzled source, linear dest, 2-way-free reads.
//   B (Wp bf16): staged once per block per step via global_load_lds
//     (134 MB total, was 536) — fragment-major => fully linear, 0-conflict.
// 3 buffers, stage(t+2) AFTER barrier(t) (provably race-free: all waves'
// reads of buf (t+2)%3 completed before their previous barrier), counted
// vmcnt(6) — in-flight stages never drained mid-loop.
template <bool WPREP>
__global__ __launch_bounds__(512, 2) void blocklinear_kernel(
    const float* __restrict__ x, const float* __restrict__ W,
    const short* __restrict__ Wp, const float* __restrict__ bias,
    float* __restrict__ y)
{
  // XCD swizzle (bijective: 512 % 8 == 0): one nb per XCD, nt innermost
  // (2 nt-siblings share an x M-panel on one XCD's L2/L3 path).
  const int b       = blockIdx.x;
  const int logical = (b & 7) * 64 + (b >> 3);
  const int nb  = logical >> 6;
  const int rem = logical & 63;
  const int mt  = rem >> 1;    // 0..31
  const int nt  = rem & 1;     // 0..1

  const int tid  = threadIdx.x;
  const int lane = tid & 63;
  const int w    = tid >> 6;   // wave 0..7
  const int wr   = w >> 1;     // M-row 0..3 (rows wr*64..+64)
  const int hN   = w & 1;      // N-half 0..1 (cols hN*128..+128)
  const int l15  = lane & 15;
  const int k16  = lane >> 4;

  __shared__ __align__(16) float Abuf[3][BM * 32];   // 3 x 32 KB
  __shared__ __align__(16) short Bbuf[3][BN * 32];   // 3 x 16 KB  (144 KB total)

  // --- A staging: 32 x 1KB DMA instrs cover 256 rows; wave w does 4 (i=0..3),
  // rows w*32+i*8 .. +8. lane l -> row +(l>>3), dest chunk l&7 (linear);
  // source pre-swizzled chunk (l&7)^(l>>3): stored slot s = data chunk s^(row&7).
  const int l8 = lane >> 3;
  const int c  = lane & 7;
  const float* asrc[4];
#pragma unroll
  for (int i = 0; i < 4; ++i) {
    const int gr = mt * BM + w * 32 + i * 8 + l8;
    asrc[i] = x + (size_t)gr * NFEAT + nb * DIN + ((c ^ l8) << 2);
  }
  // --- B staging: 16 x 1KB chunks (one per 16-col frag); wave w does 2.
  const short* bsrc[2];
#pragma unroll
  for (int i = 0; i < 2; ++i) {
    const int cb = nt * 16 + w * 2 + i;
    bsrc[i] = WPREP ? Wp + ((size_t)(nb * 32 + cb) * 16) * 512 + lane * 8 : nullptr;
  }

#define STAGE(buf, t)                                                       \
  {                                                                         \
    _Pragma("unroll")                                                       \
    for (int i = 0; i < 4; ++i)                                             \
      gload_lds16(asrc[i] + (t) * 32, &Abuf[buf][(w * 32 + i * 8) * 32]);   \
    if constexpr (WPREP) {                                                  \
      _Pragma("unroll")                                                     \
      for (int i = 0; i < 2; ++i)                                           \
        gload_lds16(bsrc[i] + (t) * 512, &Bbuf[buf][(w * 2 + i) * 512]);    \
    }                                                                       \
  }

  // --- A fragment read offsets (floats): row_local = wr*64 + m*16 + l15,
  // addr = row_local*32 + slot*4, slot = (2k16 / 2k16+1) ^ (l15&7).
  const int ra_base = (wr * 64 + l15) * 32;
  const int ra_lo   = ra_base + (((2 * k16)     ^ (l15 & 7)) << 2);
  const int ra_hi   = ra_base + (((2 * k16 + 1) ^ (l15 & 7)) << 2);

  f32x4 acc[4][8];
#pragma unroll
  for (int m = 0; m < 4; ++m)
#pragma unroll
    for (int n = 0; n < 8; ++n)
      acc[m][n] = (f32x4){0.f, 0.f, 0.f, 0.f};

#define COMPUTE(buf)                                                        \
  {                                                                         \
    const float* la = &Abuf[buf][0];                                        \
    const short* lb = &Bbuf[buf][0];                                        \
    short8 af[4], bf[8];                                                    \
    _Pragma("unroll")                                                       \
    for (int m = 0; m < 4; ++m) {                                           \
      f32x4 lo = *(const f32x4*)(la + m * 512 + ra_lo);                     \
      f32x4 hi = *(const f32x4*)(la + m * 512 + ra_hi);                     \
      af[m] = cvt8(lo, hi);                                                 \
    }                                                                       \
    if constexpr (WPREP) {                                                  \
      _Pragma("unroll")                                                     \
      for (int n = 0; n < 8; ++n)                                           \
        bf[n] = *(const short8*)(lb + (hN * 8 + n) * 512 + lane * 8);       \
    }                                                                       \
    _Pragma("unroll")                                                       \
    for (int n = 0; n < 8 && !WPREP; ++n) {                                 \
      const int col = nt * BN + hN * 128 + n * 16 + l15;                    \
      const float* bp = W + (size_t)nb * DOUT * DIN + (size_t)col * DIN +   \
                        CUR_T * 32 + k16 * 8;                               \
      bf[n] = cvt8(*(const f32x4*)bp, *(const f32x4*)(bp + 4));             \
    }                                                                       \
    __builtin_amdgcn_s_setprio(1);                                          \
    _Pragma("unroll")                                                       \
    for (int m = 0; m < 4; ++m)                                             \
      _Pragma("unroll")                                                     \
      for (int n = 0; n < 8; ++n)                                           \
        acc[m][n] = __builtin_amdgcn_mfma_f32_16x16x32_bf16(af[m], bf[n], acc[m][n], 0, 0, 0); \
    __builtin_amdgcn_s_setprio(0);                                          \
  }

  // Step t: wait own step-t stages (vmcnt: 12 outstanding -> 6 = t+1's stay
  // in flight); barrier (=> ALL waves' t-stages visible); stage(t+2) into the
  // buffer everyone finished reading at t-1; compute(t).
#define STEP(t, VMC)                                                        \
  {                                                                         \
    constexpr int CUR_T = (t);                                              \
    (void)CUR_T;                                                            \
    __builtin_amdgcn_sched_barrier(0);                                      \
    asm volatile("s_waitcnt vmcnt(" #VMC ")" ::: "memory");                 \
    __builtin_amdgcn_s_barrier();                                           \
    __builtin_amdgcn_sched_barrier(0);                                      \
    if ((t) + 2 < NT) STAGE(((t) + 2) % 3, (t) + 2);                        \
    COMPUTE((t) % 3);                                                       \
  }

  STAGE(0, 0);
  STAGE(1, 1);

  if constexpr (WPREP) {
    STEP(0, 6)  STEP(1, 6)  STEP(2, 6)  STEP(3, 6)
    STEP(4, 6)  STEP(5, 6)  STEP(6, 6)  STEP(7, 6)
    STEP(8, 6)  STEP(9, 6)  STEP(10, 6) STEP(11, 6)
    STEP(12, 6) STEP(13, 6) STEP(14, 6) STEP(15, 0)
  } else {
    STEP(0, 0)  STEP(1, 0)  STEP(2, 0)  STEP(3, 0)
    STEP(4, 0)  STEP(5, 0)  STEP(6, 0)  STEP(7, 0)
    STEP(8, 0)  STEP(9, 0)  STEP(10, 0) STEP(11, 0)
    STEP(12, 0) STEP(13, 0) STEP(14, 0) STEP(15, 0)
  }

  // epilogue: C/D layout col = lane&15, row = (lane>>4)*4 + j  [m89-verified]
  const int col0 = nt * BN + hN * 128;
  const int row0 = mt * BM + wr * 64;
  const float* bptr = bias + nb * DOUT + col0;
#pragma unroll
  for (int n = 0; n < 8; ++n) {
    const float bv = bptr[n * 16 + l15];
    const size_t col = (size_t)nb * DOUT + col0 + n * 16 + l15;
#pragma unroll
    for (int m = 0; m < 4; ++m) {
      const int row = row0 + m * 16 + k16 * 4;
      float* yp = y + (size_t)row * NFEAT + col;
#pragma unroll
      for (int j = 0; j < 4; ++j)
        yp[(size_t)j * NFEAT] = acc[m][n][j] + bv;
    }
  }
}

extern "C" void kernel_launch(void* const* d_in, const int* in_sizes, int n_in,
                              void* d_out, int out_size, void* d_ws, size_t ws_size,
                              hipStream_t stream) {
  const float* x  = (const float*)d_in[0];
  const float* W  = (const float*)d_in[1];
  const float* bi = (const float*)d_in[2];
  float* y = (float*)d_out;
  const size_t wp_bytes = (size_t)NBLK * DOUT * DIN * sizeof(short);  // 4 MiB
  const int grid = NBLK * (BATCH / BM) * (DOUT / BN);                 // 512

  if (ws_size >= wp_bytes) {
    short* Wp = (short*)d_ws;
    wprep_kernel<<<(NBLK * DOUT * DIN / 8) / 256, 256, 0, stream>>>(W, Wp);
    blocklinear_kernel<true><<<grid, 512, 0, stream>>>(x, W, Wp, bi, y);
  } else {
    blocklinear_kernel<false><<<grid, 512, 0, stream>>>(x, W, nullptr, bi, y);
  }
}